// Round 8
// baseline (212.867 us; speedup 1.0000x reference)
//
#include <hip/hip_runtime.h>

typedef __bf16 bf16x8 __attribute__((ext_vector_type(8)));
typedef __bf16 bf16x4 __attribute__((ext_vector_type(4)));
typedef float f32x4 __attribute__((ext_vector_type(4)));
typedef float f32x16 __attribute__((ext_vector_type(16)));

__device__ __forceinline__ void async16(void* lds, const void* g) {
  __builtin_amdgcn_global_load_lds(
      (__attribute__((address_space(1))) unsigned int*)(g),
      (__attribute__((address_space(3))) unsigned int*)(lds), 16, 0, 0);
}

// Per-block dtype self-detect on a 2048-u16 window.
__device__ __forceinline__ int detect_block(const unsigned short* win, int* cnt_sh) {
  if (threadIdx.x == 0) *cnt_sh = 0;
  __syncthreads();
  int c = 0;
#pragma unroll
  for (int j = 0; j < 8; j++) {
    const unsigned short u = win[threadIdx.x * 8 + j];
    if (((u >> 7) & 0xFF) >= 0xC0) c++;
  }
  if (c) atomicAdd(cnt_sh, c);
  __syncthreads();
  return (*cnt_sh >= 64) ? 1 : 0;
}

// ---------------- prep: x->bf16 cvt (blocks 0..2047) + Wqkv transpose
// (2048..2815) + Wout transpose (2816..3071), all self-detecting dtype.
__global__ __launch_bounds__(256) void prep(
    const void* __restrict__ x, const void* __restrict__ Wqkv,
    const void* __restrict__ Wout, __bf16* __restrict__ xb,
    __bf16* __restrict__ WqkvT, __bf16* __restrict__ WoutT,
    int* __restrict__ flagp)
{
  __shared__ __bf16 tile[64 * 65];
  __shared__ int cnt;
  const int bx = blockIdx.x;
  const int t = threadIdx.x;

  if (bx < 2048) {
    const long base = (long)bx * 2048;
    const int f = detect_block((const unsigned short*)x + base, &cnt);
    if (bx == 0 && t == 0) *flagp = f;
    const long i = base + t * 8;
    if (f) {
      const float* s = (const float*)x;
#pragma unroll
      for (int j = 0; j < 8; j++) xb[i + j] = (__bf16)s[i + j];
    } else {
      *(bf16x8*)&xb[i] = *(const bf16x8*)((const __bf16*)x + i);
    }
    return;
  }

  const void* in;  __bf16* out;  int R = 1024, C, tcx, tr;
  if (bx < 2816) {
    const int idx = bx - 2048;
    in = Wqkv; out = WqkvT; C = 3072; tcx = (idx % 48) * 64; tr = (idx / 48) * 64;
  } else {
    const int idx = bx - 2816;
    in = Wout; out = WoutT; C = 1024; tcx = (idx % 16) * 64; tr = (idx / 16) * 64;
  }
  const int f = detect_block((const unsigned short*)in + (long)tr * C + tcx, &cnt);
#pragma unroll
  for (int i = 0; i < 16; i++) {
    const int idx = t + 256 * i;
    const int r = idx >> 6, c = idx & 63;
    const long g = (long)(tr + r) * C + tcx + c;
    tile[r * 65 + c] = f ? (__bf16)((const float*)in)[g] : ((const __bf16*)in)[g];
  }
  __syncthreads();
#pragma unroll
  for (int i = 0; i < 16; i++) {
    const int idx = t + 256 * i;
    const int r = idx >> 6, c = idx & 63;
    out[(long)(tcx + r) * R + tr + c] = tile[c * 65 + r];
  }
}

// ---------------- qkv GEMM: [4096,1024] x [1024,3072]^T, prefetch-pipelined
// (one barrier/iter, K/V DMA one tile ahead). Q,K -> qk (stride 2048);
// V -> Vt[bh*64+d][2048] via padded-LDS transpose.
__global__ __launch_bounds__(256, 3) void gemm_qkv(
    const __bf16* __restrict__ A, const __bf16* __restrict__ Bt,
    __bf16* __restrict__ Cqk, __bf16* __restrict__ Vt)
{
  __shared__ __bf16 smem[17408];   // dbuf: A0@0 B0@4096 A1@8192 B1@12288 (elems); vtile after loop
  const int t = threadIdx.x;
  const int l = t & 63;
  const int w = t >> 6;
  const int wr = w >> 1, wc = w & 1;
  const long m0 = (long)blockIdx.x * 128;
  const long n0 = (long)blockIdx.y * 128;
  const int K = 1024;

  const int srow = w * 16 + (l >> 2);
  const int skof = (l & 3) * 8;
  const __bf16* gA = A + (m0 + srow) * (long)K + skof;
  const __bf16* gB = Bt + (n0 + srow) * (long)K + skof;
  const int Ao[2] = {0, 8192}, Bo[2] = {4096, 12288};
  const int lof = w * 512 + l * 8;

  // prolog: stage tile 0
  async16(smem + Ao[0] + lof,        gA);
  async16(smem + Ao[0] + 2048 + lof, gA + 64 * (long)K);
  async16(smem + Bo[0] + lof,        gB);
  async16(smem + Bo[0] + 2048 + lof, gB + 64 * (long)K);
  gA += 32; gB += 32;
  __syncthreads();

  f32x4 acc[4][4] = {};

  for (int it = 0; it < 32; it++) {
    if (it < 31) {
      const int nb = (it + 1) & 1;
      async16(smem + Ao[nb] + lof,        gA);
      async16(smem + Ao[nb] + 2048 + lof, gA + 64 * (long)K);
      async16(smem + Bo[nb] + lof,        gB);
      async16(smem + Bo[nb] + 2048 + lof, gB + 64 * (long)K);
      gA += 32; gB += 32;
    }
    const __bf16* As = smem + Ao[it & 1];
    const __bf16* Bs = smem + Bo[it & 1];
    bf16x8 af[4], bfr[4];
#pragma unroll
    for (int mi = 0; mi < 4; mi++)
      af[mi] = *(const bf16x8*)&As[(wr * 64 + mi * 16 + (l & 15)) * 32 + (l >> 4) * 8];
#pragma unroll
    for (int ni = 0; ni < 4; ni++)
      bfr[ni] = *(const bf16x8*)&Bs[(wc * 64 + ni * 16 + (l & 15)) * 32 + (l >> 4) * 8];
#pragma unroll
    for (int mi = 0; mi < 4; mi++)
#pragma unroll
      for (int ni = 0; ni < 4; ni++)
        acc[mi][ni] = __builtin_amdgcn_mfma_f32_16x16x32_bf16(af[mi], bfr[ni], acc[mi][ni], 0, 0, 0);
    __syncthreads();   // drains prefetch (overlapped with MFMA) + guards reuse
  }

  if (n0 < 2048) {
#pragma unroll
    for (int mi = 0; mi < 4; mi++)
#pragma unroll
      for (int ni = 0; ni < 4; ni++) {
        const long col = n0 + wc * 64 + ni * 16 + (l & 15);
#pragma unroll
        for (int r = 0; r < 4; r++) {
          const long row = m0 + wr * 64 + mi * 16 + (l >> 4) * 4 + r;
          Cqk[row * 2048 + col] = (__bf16)acc[mi][ni][r];
        }
      }
  } else {
    // V block: transpose via padded LDS (stride 136), coalesced Vt row writes
#pragma unroll
    for (int mi = 0; mi < 4; mi++)
#pragma unroll
      for (int ni = 0; ni < 4; ni++) {
        const int c = wc * 64 + ni * 16 + (l & 15);
        const int r = wr * 64 + mi * 16 + (l >> 4) * 4;
        bf16x4 pk;
#pragma unroll
        for (int k = 0; k < 4; k++) pk[k] = (__bf16)acc[mi][ni][k];
        *(bf16x4*)&smem[c * 136 + r] = pk;
      }
    __syncthreads();
    const int b = (int)(m0 >> 11);
    const int nbase = (int)(m0 & 2047);
#pragma unroll
    for (int i = 0; i < 8; i++) {
      const int c = (t >> 4) + i * 16;
      const int r8 = (t & 15) * 8;
      const bf16x8 v = *(const bf16x8*)&smem[c * 136 + r8];
      const int vcol = (int)(n0 - 2048) + c;
      *(bf16x8*)&Vt[((long)(b * 16 + (vcol >> 6)) * 64 + (vcol & 63)) * 2048 + nbase + r8] = v;
    }
  }
}

// ---------------- out GEMM: [4096,1024] x [1024,1024]^T + bias, 128x64 tile,
// prefetch-pipelined, 512 blocks.
__global__ __launch_bounds__(256, 2) void gemm_out(
    const __bf16* __restrict__ A, const __bf16* __restrict__ Bt,
    const void* __restrict__ bias_raw, void* __restrict__ C,
    const int* __restrict__ flagp)
{
  __shared__ __bf16 smem[12288];  // A0@0 B0@4096 A1@6144 B1@10240
  const int t = threadIdx.x;
  const int l = t & 63;
  const int w = t >> 6;
  const int wr = w >> 1, wc = w & 1;
  const long m0 = (long)blockIdx.x * 128;
  const long n0 = (long)blockIdx.y * 64;
  const int of = *flagp;
  const int K = 1024;

  const int srow = w * 16 + (l >> 2);
  const int skof = (l & 3) * 8;
  const __bf16* gA = A + (m0 + srow) * (long)K + skof;
  const __bf16* gB = Bt + (n0 + srow) * (long)K + skof;
  const int Ao[2] = {0, 6144}, Bo[2] = {4096, 10240};
  const int lof = w * 512 + l * 8;

  async16(smem + Ao[0] + lof,        gA);
  async16(smem + Ao[0] + 2048 + lof, gA + 64 * (long)K);
  async16(smem + Bo[0] + lof,        gB);
  gA += 32; gB += 32;
  __syncthreads();

  f32x4 acc[4][2] = {};

  for (int it = 0; it < 32; it++) {
    if (it < 31) {
      const int nb = (it + 1) & 1;
      async16(smem + Ao[nb] + lof,        gA);
      async16(smem + Ao[nb] + 2048 + lof, gA + 64 * (long)K);
      async16(smem + Bo[nb] + lof,        gB);
      gA += 32; gB += 32;
    }
    const __bf16* As = smem + Ao[it & 1];
    const __bf16* Bs = smem + Bo[it & 1];
    bf16x8 af[4], bfr[2];
#pragma unroll
    for (int mi = 0; mi < 4; mi++)
      af[mi] = *(const bf16x8*)&As[(wr * 64 + mi * 16 + (l & 15)) * 32 + (l >> 4) * 8];
#pragma unroll
    for (int ni = 0; ni < 2; ni++)
      bfr[ni] = *(const bf16x8*)&Bs[(wc * 32 + ni * 16 + (l & 15)) * 32 + (l >> 4) * 8];
#pragma unroll
    for (int mi = 0; mi < 4; mi++)
#pragma unroll
      for (int ni = 0; ni < 2; ni++)
        acc[mi][ni] = __builtin_amdgcn_mfma_f32_16x16x32_bf16(af[mi], bfr[ni], acc[mi][ni], 0, 0, 0);
    __syncthreads();
  }

#pragma unroll
  for (int mi = 0; mi < 4; mi++)
#pragma unroll
    for (int ni = 0; ni < 2; ni++) {
      const long col = n0 + wc * 32 + ni * 16 + (l & 15);
      const float bv = of ? ((const float*)bias_raw)[col]
                          : (float)((const __bf16*)bias_raw)[col];
#pragma unroll
      for (int r = 0; r < 4; r++) {
        const long row = m0 + wr * 64 + mi * 16 + (l >> 4) * 4 + r;
        const float val = acc[mi][ni][r] + bv;
        const long off = row * 1024 + col;
        if (of) ((float*)C)[off] = val;
        else    ((__bf16*)C)[off] = (__bf16)val;
      }
    }
}

// ---------------- flash attention: quadrant 32x32x16, K/V double-buffered
// prefetch (1 barrier/iter), in-register P transpose (no Ps LDS round-trip).
// Wave (wi,wj): St quadrant [j in wj-half][i in wi-half]; partial O over its
// j-half for full d=64; cross-wj combine in epilogue.
#define EXP2_SCALE 0.045084439f   // (1/32) * log2(e)

__global__ __launch_bounds__(256, 4) void attn_kernel(
    const __bf16* __restrict__ qk, const __bf16* __restrict__ Vt,
    __bf16* __restrict__ O)
{
  __shared__ __bf16 smem[20480];  // Qs@0 Ka@4096 Va@8192 Kb@12288 Vb@16384 (elems)
  const int t = threadIdx.x;
  const int l = t & 63;
  const int w = t >> 6;
  const int wi = w & 1, wj = w >> 1;
  const int hl = l >> 5;           // half-wave
  const int i7 = l & 7;
  const int qt = blockIdx.x;       // 0..31
  const int bh = blockIdx.y;       // 0..31
  const int b = bh >> 4, head = bh & 15;
  const long q_row0 = (long)b * 2048 + qt * 64;

  const int srow = w * 8 + (l >> 3);
  const int sdof = ((l & 7) ^ (l >> 3)) * 8;
  const int lof = w * 512 + l * 8;
  const int Ko[2] = {4096, 12288}, Vo[2] = {8192, 16384};

  // prolog: Q + tile 0
  {
    const __bf16* g = qk + (q_row0 + srow) * 2048 + head * 64 + sdof;
    async16(smem + lof,        g);
    async16(smem + 2048 + lof, g + (long)32 * 2048);
  }
  const __bf16* gK = qk + ((long)b * 2048 + srow) * 2048 + 1024 + head * 64 + sdof;
  const __bf16* gV = Vt + ((long)bh * 64 + srow) * 2048 + sdof;
  async16(smem + Ko[0] + lof,        gK);
  async16(smem + Ko[0] + 2048 + lof, gK + 32 * 2048);
  async16(smem + Vo[0] + lof,        gV);
  async16(smem + Vo[0] + 2048 + lof, gV + 32 * 2048);
  gK += (long)64 * 2048;
  gV += 64;
  __syncthreads();

  // hoist Q fragments: B-operand of St, rows i = wi*32+(l&31)
  bf16x8 qf[4];
#pragma unroll
  for (int kc = 0; kc < 4; kc++)
    qf[kc] = *(const bf16x8*)&smem[(wi * 32 + (l & 31)) * 64 + (((kc * 2 + hl) ^ i7) * 8)];

  f32x16 acc[2] = {};
  float l_i = 0.0f;

  for (int it = 0; it < 32; it++) {
    if (it < 31) {
      const int nb = (it + 1) & 1;
      async16(smem + Ko[nb] + lof,        gK);
      async16(smem + Ko[nb] + 2048 + lof, gK + 32 * 2048);
      async16(smem + Vo[nb] + lof,        gV);
      async16(smem + Vo[nb] + 2048 + lof, gV + 32 * 2048);
      gK += (long)64 * 2048;
      gV += 64;
    }
    const __bf16* Ks = smem + Ko[it & 1];
    const __bf16* Vs = smem + Vo[it & 1];

    // St[j][i] quadrant
    f32x16 st = {0,0,0,0,0,0,0,0,0,0,0,0,0,0,0,0};
#pragma unroll
    for (int kc = 0; kc < 4; kc++) {
      const bf16x8 ak = *(const bf16x8*)&Ks[(wj * 32 + (l & 31)) * 64 + (((kc * 2 + hl) ^ i7) * 8)];
      st = __builtin_amdgcn_mfma_f32_32x32x16_bf16(ak, qf[kc], st, 0, 0, 0);
    }

    // exp + row-sum (lane owns 16 scores of query i = wi*32+(l&31))
    float rs = 0.0f;
#pragma unroll
    for (int r = 0; r < 16; r++) {
      const float p = exp2f(st[r] * EXP2_SCALE);
      st[r] = p;
      rs += p;
    }
    rs += __shfl_xor(rs, 32, 64);
    l_i += rs;

    // pack P to bf16 pairs, exchange halves, build A-frags in-register
    unsigned pw[8], qw[8];
#pragma unroll
    for (int k2 = 0; k2 < 8; k2++) {
      union { __bf16 h2[2]; unsigned u; } cv;
      cv.h2[0] = (__bf16)st[2 * k2];
      cv.h2[1] = (__bf16)st[2 * k2 + 1];
      pw[k2] = cv.u;
    }
#pragma unroll
    for (int k2 = 0; k2 < 8; k2++)
      qw[k2] = (unsigned)__shfl_xor((int)pw[k2], 32, 64);

#pragma unroll
    for (int m = 0; m < 2; m++) {
      union { unsigned u[4]; bf16x8 v; } fa;
      fa.u[0] = hl ? qw[4 * m + 2] : pw[4 * m + 0];
      fa.u[1] = hl ? qw[4 * m + 3] : pw[4 * m + 1];
      fa.u[2] = hl ? pw[4 * m + 2] : qw[4 * m + 0];
      fa.u[3] = hl ? pw[4 * m + 3] : qw[4 * m + 1];
#pragma unroll
      for (int nd = 0; nd < 2; nd++) {
        const bf16x8 bv = *(const bf16x8*)&Vs[(nd * 32 + (l & 31)) * 64 + (((4 * wj + 2 * m + hl) ^ i7) * 8)];
        acc[nd] = __builtin_amdgcn_mfma_f32_32x32x16_bf16(fa.v, bv, acc[nd], 0, 0, 0);
      }
    }
    __syncthreads();   // drains prefetch (overlapped) + guards buffer reuse
  }

  // epilogue: cross-wj combine via LDS, normalize, store
  float* sc = (float*)(smem + 4096);     // 16KB scratch (Ka+Va region)
  float* lb = (float*)(smem + 12288);    // 128 floats (Kb region)
  if (l < 32) lb[w * 32 + l] = l_i;
  if (wj == 1) {
#pragma unroll
    for (int nd = 0; nd < 2; nd++)
#pragma unroll
      for (int r = 0; r < 16; r++)
        sc[wi * 2048 + nd * 1024 + (int)l * 16 + r] = acc[nd][r];
  }
  __syncthreads();
  if (wj == 0) {
#pragma unroll
    for (int r = 0; r < 16; r++) {
      const int iloc = (r & 3) + 8 * (r >> 2) + 4 * hl;
      const float lt = lb[wi * 32 + iloc] + lb[(wi + 2) * 32 + iloc];
      const long row = q_row0 + wi * 32 + iloc;
#pragma unroll
      for (int nd = 0; nd < 2; nd++) {
        const float o = acc[nd][r] + sc[wi * 2048 + nd * 1024 + (int)l * 16 + r];
        O[row * 1024 + head * 64 + nd * 32 + (l & 31)] = (__bf16)(o / lt);
      }
    }
  }
}

extern "C" void kernel_launch(void* const* d_in, const int* in_sizes, int n_in,
                              void* d_out, int out_size, void* d_ws, size_t ws_size,
                              hipStream_t stream) {
  const void* x    = d_in[0];   // [2,2048,1024]  fp32 or bf16 (runtime-detected)
  const void* Wqkv = d_in[1];   // [1024,3072]
  const void* Wout = d_in[2];   // [1024,1024]
  const void* bout = d_in[3];   // [1024]

  char* ws = (char*)d_ws;
  int*    flagp = (int*)ws;                                  // 4 B
  __bf16* xb    = (__bf16*)(ws + 4096);                      //  8 MB
  __bf16* WqkvT = (__bf16*)(ws + 4096 +  8388608);           //  6 MB
  __bf16* WoutT = (__bf16*)(ws + 4096 + 14680064);           //  2 MB
  __bf16* qkbuf = (__bf16*)(ws + 4096 + 16777216);           // 16 MB (Q,K stride 2048)
  __bf16* VtBuf = (__bf16*)(ws + 4096 + 33554432);           //  8 MB
  __bf16* Obuf  = (__bf16*)(ws + 4096 + 41943040);           //  8 MB

  hipLaunchKernelGGL(prep, dim3(3072), dim3(256), 0, stream,
                     x, Wqkv, Wout, xb, WqkvT, WoutT, flagp);
  hipLaunchKernelGGL(gemm_qkv, dim3(32, 24), dim3(256), 0, stream,
                     xb, WqkvT, qkbuf, VtBuf);
  hipLaunchKernelGGL(attn_kernel, dim3(32, 32), dim3(256), 0, stream,
                     qkbuf, VtBuf, Obuf);
  hipLaunchKernelGGL(gemm_out, dim3(32, 16), dim3(256), 0, stream,
                     Obuf, WoutT, bout, d_out, flagp);
}

// Round 10
// 200.565 us; speedup vs baseline: 1.0613x; 1.0613x over previous
//
#include <hip/hip_runtime.h>

typedef __bf16 bf16x8 __attribute__((ext_vector_type(8)));
typedef __bf16 bf16x4 __attribute__((ext_vector_type(4)));
typedef float f32x4 __attribute__((ext_vector_type(4)));
typedef float f32x16 __attribute__((ext_vector_type(16)));

__device__ __forceinline__ void async16(void* lds, const void* g) {
  __builtin_amdgcn_global_load_lds(
      (__attribute__((address_space(1))) unsigned int*)(g),
      (__attribute__((address_space(3))) unsigned int*)(lds), 16, 0, 0);
}

// Per-block dtype self-detect on a 2048-u16 window.
__device__ __forceinline__ int detect_block(const unsigned short* win, int* cnt_sh) {
  if (threadIdx.x == 0) *cnt_sh = 0;
  __syncthreads();
  int c = 0;
#pragma unroll
  for (int j = 0; j < 8; j++) {
    const unsigned short u = win[threadIdx.x * 8 + j];
    if (((u >> 7) & 0xFF) >= 0xC0) c++;
  }
  if (c) atomicAdd(cnt_sh, c);
  __syncthreads();
  return (*cnt_sh >= 64) ? 1 : 0;
}

// ---------------- prep: x->bf16 cvt (blocks 0..2047) + Wqkv transpose
// (2048..2815) + Wout transpose (2816..3071), all self-detecting dtype.
__global__ __launch_bounds__(256) void prep(
    const void* __restrict__ x, const void* __restrict__ Wqkv,
    const void* __restrict__ Wout, __bf16* __restrict__ xb,
    __bf16* __restrict__ WqkvT, __bf16* __restrict__ WoutT,
    int* __restrict__ flagp)
{
  __shared__ __bf16 tile[64 * 65];
  __shared__ int cnt;
  const int bx = blockIdx.x;
  const int t = threadIdx.x;

  if (bx < 2048) {
    const long base = (long)bx * 2048;
    const int f = detect_block((const unsigned short*)x + base, &cnt);
    if (bx == 0 && t == 0) *flagp = f;
    const long i = base + t * 8;
    if (f) {
      const float* s = (const float*)x;
#pragma unroll
      for (int j = 0; j < 8; j++) xb[i + j] = (__bf16)s[i + j];
    } else {
      *(bf16x8*)&xb[i] = *(const bf16x8*)((const __bf16*)x + i);
    }
    return;
  }

  const void* in;  __bf16* out;  int R = 1024, C, tcx, tr;
  if (bx < 2816) {
    const int idx = bx - 2048;
    in = Wqkv; out = WqkvT; C = 3072; tcx = (idx % 48) * 64; tr = (idx / 48) * 64;
  } else {
    const int idx = bx - 2816;
    in = Wout; out = WoutT; C = 1024; tcx = (idx % 16) * 64; tr = (idx / 16) * 64;
  }
  const int f = detect_block((const unsigned short*)in + (long)tr * C + tcx, &cnt);
#pragma unroll
  for (int i = 0; i < 16; i++) {
    const int idx = t + 256 * i;
    const int r = idx >> 6, c = idx & 63;
    const long g = (long)(tr + r) * C + tcx + c;
    tile[r * 65 + c] = f ? (__bf16)((const float*)in)[g] : ((const __bf16*)in)[g];
  }
  __syncthreads();
#pragma unroll
  for (int i = 0; i < 16; i++) {
    const int idx = t + 256 * i;
    const int r = idx >> 6, c = idx & 63;
    out[(long)(tcx + r) * R + tr + c] = tile[c * 65 + r];
  }
}

// ---------------- qkv GEMM: [4096,1024] x [1024,3072]^T, prefetch-pipelined.
// Q,K -> qk (stride 2048); V -> Vt[bh*64+d][2048] via padded-LDS transpose.
__global__ __launch_bounds__(256, 3) void gemm_qkv(
    const __bf16* __restrict__ A, const __bf16* __restrict__ Bt,
    __bf16* __restrict__ Cqk, __bf16* __restrict__ Vt)
{
  __shared__ __bf16 smem[17408];
  const int t = threadIdx.x;
  const int l = t & 63;
  const int w = t >> 6;
  const int wr = w >> 1, wc = w & 1;
  const long m0 = (long)blockIdx.x * 128;
  const long n0 = (long)blockIdx.y * 128;
  const int K = 1024;

  const int srow = w * 16 + (l >> 2);
  const int skof = (l & 3) * 8;
  const __bf16* gA = A + (m0 + srow) * (long)K + skof;
  const __bf16* gB = Bt + (n0 + srow) * (long)K + skof;
  const int Ao[2] = {0, 8192}, Bo[2] = {4096, 12288};
  const int lof = w * 512 + l * 8;

  async16(smem + Ao[0] + lof,        gA);
  async16(smem + Ao[0] + 2048 + lof, gA + 64 * (long)K);
  async16(smem + Bo[0] + lof,        gB);
  async16(smem + Bo[0] + 2048 + lof, gB + 64 * (long)K);
  gA += 32; gB += 32;
  __syncthreads();

  f32x4 acc[4][4] = {};

  for (int it = 0; it < 32; it++) {
    if (it < 31) {
      const int nb = (it + 1) & 1;
      async16(smem + Ao[nb] + lof,        gA);
      async16(smem + Ao[nb] + 2048 + lof, gA + 64 * (long)K);
      async16(smem + Bo[nb] + lof,        gB);
      async16(smem + Bo[nb] + 2048 + lof, gB + 64 * (long)K);
      gA += 32; gB += 32;
    }
    const __bf16* As = smem + Ao[it & 1];
    const __bf16* Bs = smem + Bo[it & 1];
    bf16x8 af[4], bfr[4];
#pragma unroll
    for (int mi = 0; mi < 4; mi++)
      af[mi] = *(const bf16x8*)&As[(wr * 64 + mi * 16 + (l & 15)) * 32 + (l >> 4) * 8];
#pragma unroll
    for (int ni = 0; ni < 4; ni++)
      bfr[ni] = *(const bf16x8*)&Bs[(wc * 64 + ni * 16 + (l & 15)) * 32 + (l >> 4) * 8];
#pragma unroll
    for (int mi = 0; mi < 4; mi++)
#pragma unroll
      for (int ni = 0; ni < 4; ni++)
        acc[mi][ni] = __builtin_amdgcn_mfma_f32_16x16x32_bf16(af[mi], bfr[ni], acc[mi][ni], 0, 0, 0);
    __syncthreads();
  }

  if (n0 < 2048) {
#pragma unroll
    for (int mi = 0; mi < 4; mi++)
#pragma unroll
      for (int ni = 0; ni < 4; ni++) {
        const long col = n0 + wc * 64 + ni * 16 + (l & 15);
#pragma unroll
        for (int r = 0; r < 4; r++) {
          const long row = m0 + wr * 64 + mi * 16 + (l >> 4) * 4 + r;
          Cqk[row * 2048 + col] = (__bf16)acc[mi][ni][r];
        }
      }
  } else {
#pragma unroll
    for (int mi = 0; mi < 4; mi++)
#pragma unroll
      for (int ni = 0; ni < 4; ni++) {
        const int c = wc * 64 + ni * 16 + (l & 15);
        const int r = wr * 64 + mi * 16 + (l >> 4) * 4;
        bf16x4 pk;
#pragma unroll
        for (int k = 0; k < 4; k++) pk[k] = (__bf16)acc[mi][ni][k];
        *(bf16x4*)&smem[c * 136 + r] = pk;
      }
    __syncthreads();
    const int b = (int)(m0 >> 11);
    const int nbase = (int)(m0 & 2047);
#pragma unroll
    for (int i = 0; i < 8; i++) {
      const int c = (t >> 4) + i * 16;
      const int r8 = (t & 15) * 8;
      const bf16x8 v = *(const bf16x8*)&smem[c * 136 + r8];
      const int vcol = (int)(n0 - 2048) + c;
      *(bf16x8*)&Vt[((long)(b * 16 + (vcol >> 6)) * 64 + (vcol & 63)) * 2048 + nbase + r8] = v;
    }
  }
}

// ---------------- out GEMM: [4096,1024] x [1024,1024]^T + bias, 128x64 tile.
__global__ __launch_bounds__(256, 2) void gemm_out(
    const __bf16* __restrict__ A, const __bf16* __restrict__ Bt,
    const void* __restrict__ bias_raw, void* __restrict__ C,
    const int* __restrict__ flagp)
{
  __shared__ __bf16 smem[12288];
  const int t = threadIdx.x;
  const int l = t & 63;
  const int w = t >> 6;
  const int wr = w >> 1, wc = w & 1;
  const long m0 = (long)blockIdx.x * 128;
  const long n0 = (long)blockIdx.y * 64;
  const int of = *flagp;
  const int K = 1024;

  const int srow = w * 16 + (l >> 2);
  const int skof = (l & 3) * 8;
  const __bf16* gA = A + (m0 + srow) * (long)K + skof;
  const __bf16* gB = Bt + (n0 + srow) * (long)K + skof;
  const int Ao[2] = {0, 6144}, Bo[2] = {4096, 10240};
  const int lof = w * 512 + l * 8;

  async16(smem + Ao[0] + lof,        gA);
  async16(smem + Ao[0] + 2048 + lof, gA + 64 * (long)K);
  async16(smem + Bo[0] + lof,        gB);
  gA += 32; gB += 32;
  __syncthreads();

  f32x4 acc[4][2] = {};

  for (int it = 0; it < 32; it++) {
    if (it < 31) {
      const int nb = (it + 1) & 1;
      async16(smem + Ao[nb] + lof,        gA);
      async16(smem + Ao[nb] + 2048 + lof, gA + 64 * (long)K);
      async16(smem + Bo[nb] + lof,        gB);
      gA += 32; gB += 32;
    }
    const __bf16* As = smem + Ao[it & 1];
    const __bf16* Bs = smem + Bo[it & 1];
    bf16x8 af[4], bfr[2];
#pragma unroll
    for (int mi = 0; mi < 4; mi++)
      af[mi] = *(const bf16x8*)&As[(wr * 64 + mi * 16 + (l & 15)) * 32 + (l >> 4) * 8];
#pragma unroll
    for (int ni = 0; ni < 2; ni++)
      bfr[ni] = *(const bf16x8*)&Bs[(wc * 32 + ni * 16 + (l & 15)) * 32 + (l >> 4) * 8];
#pragma unroll
    for (int mi = 0; mi < 4; mi++)
#pragma unroll
      for (int ni = 0; ni < 2; ni++)
        acc[mi][ni] = __builtin_amdgcn_mfma_f32_16x16x32_bf16(af[mi], bfr[ni], acc[mi][ni], 0, 0, 0);
    __syncthreads();
  }

#pragma unroll
  for (int mi = 0; mi < 4; mi++)
#pragma unroll
    for (int ni = 0; ni < 2; ni++) {
      const long col = n0 + wc * 32 + ni * 16 + (l & 15);
      const float bv = of ? ((const float*)bias_raw)[col]
                          : (float)((const __bf16*)bias_raw)[col];
#pragma unroll
      for (int r = 0; r < 4; r++) {
        const long row = m0 + wr * 64 + mi * 16 + (l >> 4) * 4 + r;
        const float val = acc[mi][ni][r] + bv;
        const long off = row * 1024 + col;
        if (of) ((float*)C)[off] = val;
        else    ((__bf16*)C)[off] = (__bf16)val;
      }
    }
}

// ---------------- flash attention: quadrant 32x32x16 (R7-verified math +
// R7-verified epilogue), XCD-swizzled blocks (all 32 qt-blocks of a (b,h) on
// one XCD -> K/V L2-hot), K/V double-buffered with prefetch after the mid
// barrier. Qs region recycled as Ps after the one-time qf hoist (40KB LDS).
// Each wave (wi,wj) owns the DISJOINT O quadrant [i in wi-half][d in wj-half]
// computed over full k=64; only l_i needs the cross-wj combine.
#define EXP2_SCALE 0.045084439f   // (1/32) * log2(e)

__global__ __launch_bounds__(256, 4) void attn_kernel(
    const __bf16* __restrict__ qk, const __bf16* __restrict__ Vt,
    __bf16* __restrict__ O)
{
  __shared__ __bf16 smem[20480];  // Q/Ps@0 K0@4096 V0@8192 K1@12288 V1@16384
  const int t = threadIdx.x;
  const int l = t & 63;
  const int w = t >> 6;
  const int wi = w & 1, wj = w >> 1;
  const int hl = l >> 5;
  const int i7 = l & 7;
  // XCD swizzle: same bh => same (linear % 8) => same XCD L2.
  const int L = blockIdx.y * 32 + blockIdx.x;
  const int bh = (L & 7) * 4 + ((L >> 3) & 3);
  const int qt = L >> 5;
  const int b = bh >> 4, head = bh & 15;
  const long q_row0 = (long)b * 2048 + qt * 64;

  const int srow = w * 8 + (l >> 3);
  const int sdof = ((l & 7) ^ (l >> 3)) * 8;
  const int lof = w * 512 + l * 8;
  const int Ko[2] = {4096, 12288}, Vo[2] = {8192, 16384};

  // prolog: Q + tile 0
  {
    const __bf16* g = qk + (q_row0 + srow) * 2048 + head * 64 + sdof;
    async16(smem + lof,        g);
    async16(smem + 2048 + lof, g + (long)32 * 2048);
  }
  const __bf16* gK = qk + ((long)b * 2048 + srow) * 2048 + 1024 + head * 64 + sdof;
  const __bf16* gV = Vt + ((long)bh * 64 + srow) * 2048 + sdof;
  async16(smem + Ko[0] + lof,        gK);
  async16(smem + Ko[0] + 2048 + lof, gK + 32 * 2048);
  async16(smem + Vo[0] + lof,        gV);
  async16(smem + Vo[0] + 2048 + lof, gV + 32 * 2048);
  gK += (long)64 * 2048;
  gV += 64;
  __syncthreads();                 // Q + tile0 drained

  // hoist Q fragments (B-operand of St), rows i = wi*32+(l&31); Qs dead after
  bf16x8 qf[4];
#pragma unroll
  for (int kc = 0; kc < 4; kc++)
    qf[kc] = *(const bf16x8*)&smem[(wi * 32 + (l & 31)) * 64 + (((kc * 2 + hl) ^ i7) * 8)];

  __bf16* Ps = smem;               // recycled Qs region
  f32x16 acc = {0,0,0,0,0,0,0,0,0,0,0,0,0,0,0,0};
  float l_i = 0.0f;

  for (int it = 0; it < 32; it++) {
    __syncthreads();               // drains prefetch (cur valid); Ps-reuse guard
    const __bf16* Ks = smem + Ko[it & 1];
    const __bf16* Vs = smem + Vo[it & 1];

    // St[j][i] quadrant: A = K rows (j in wj-half), B = Q rows (i in wi-half)
    f32x16 st = {0,0,0,0,0,0,0,0,0,0,0,0,0,0,0,0};
#pragma unroll
    for (int kc = 0; kc < 4; kc++) {
      const bf16x8 ak = *(const bf16x8*)&Ks[(wj * 32 + (l & 31)) * 64 + (((kc * 2 + hl) ^ i7) * 8)];
      st = __builtin_amdgcn_mfma_f32_32x32x16_bf16(ak, qf[kc], st, 0, 0, 0);
    }

    // exp + row-sum (lane owns 16 scores of query i = wi*32+(l&31))
    float rs = 0.0f;
#pragma unroll
    for (int r = 0; r < 16; r++) {
      const float p = exp2f(st[r] * EXP2_SCALE);
      st[r] = p;
      rs += p;
    }
    rs += __shfl_xor(rs, 32, 64);  // sum over this wave's full 32-j half
    l_i += rs;

    // pack P -> Ps[i][j] (A-layout rows, 16B-granule swizzle by i&7)
    {
      const int ibase = (wi * 32 + (l & 31)) * 64;
      const int sub = 4 * hl;
#pragma unroll
      for (int q = 0; q < 4; q++) {
        bf16x4 pk;
#pragma unroll
        for (int r = 0; r < 4; r++) pk[r] = (__bf16)st[q * 4 + r];
        const int gj = 4 * wj + q;
        *(bf16x4*)&Ps[ibase + ((gj ^ i7) * 8) + sub] = pk;
      }
    }
    __syncthreads();               // publish Ps (both wj halves)

    // prefetch next K/V tile (drained at next iter's entry barrier)
    if (it < 31) {
      const int nb = (it + 1) & 1;
      async16(smem + Ko[nb] + lof,        gK);
      async16(smem + Ko[nb] + 2048 + lof, gK + 32 * 2048);
      async16(smem + Vo[nb] + lof,        gV);
      async16(smem + Vo[nb] + 2048 + lof, gV + 32 * 2048);
      gK += (long)64 * 2048;
      gV += 64;
    }

    // O[i in wi-half][d in wj-half] += P·V over full k=64
#pragma unroll
    for (int kc = 0; kc < 4; kc++) {
      const int swz = ((kc * 2 + hl) ^ i7) * 8;
      const bf16x8 ap = *(const bf16x8*)&Ps[(wi * 32 + (l & 31)) * 64 + swz];
      const bf16x8 bv = *(const bf16x8*)&Vs[(wj * 32 + (l & 31)) * 64 + swz];
      acc = __builtin_amdgcn_mfma_f32_32x32x16_bf16(ap, bv, acc, 0, 0, 0);
    }
  }

  // epilogue (R7-verified): combine l_i across wj via LDS; each wave stores
  // its own disjoint O quadrant.
  __syncthreads();
  float* lb = (float*)(smem + 12288);    // 128 floats (K1 region)
  if (l < 32) lb[w * 32 + l] = l_i;      // w = 2*wj + wi
  __syncthreads();
#pragma unroll
  for (int r = 0; r < 16; r++) {
    const int iloc = (r & 3) + 8 * (r >> 2) + 4 * hl;
    const float lt = lb[wi * 32 + iloc] + lb[(wi + 2) * 32 + iloc];
    const long row = q_row0 + wi * 32 + iloc;
    const long col = (long)head * 64 + wj * 32 + (l & 31);
    O[row * 1024 + col] = (__bf16)(acc[r] / lt);
  }
}

extern "C" void kernel_launch(void* const* d_in, const int* in_sizes, int n_in,
                              void* d_out, int out_size, void* d_ws, size_t ws_size,
                              hipStream_t stream) {
  const void* x    = d_in[0];
  const void* Wqkv = d_in[1];
  const void* Wout = d_in[2];
  const void* bout = d_in[3];

  char* ws = (char*)d_ws;
  int*    flagp = (int*)ws;
  __bf16* xb    = (__bf16*)(ws + 4096);                      // 8 MB (dead after gemm_qkv)
  __bf16* Obuf  = xb;                                        // alias
  __bf16* WqkvT = (__bf16*)(ws + 4096 +  8388608);           // 6 MB
  __bf16* WoutT = (__bf16*)(ws + 4096 + 14680064);           // 2 MB
  __bf16* qkbuf = (__bf16*)(ws + 4096 + 16777216);           // 16 MB
  __bf16* VtBuf = (__bf16*)(ws + 4096 + 33554432);           // 8 MB

  hipLaunchKernelGGL(prep, dim3(3072), dim3(256), 0, stream,
                     x, Wqkv, Wout, xb, WqkvT, WoutT, flagp);
  hipLaunchKernelGGL(gemm_qkv, dim3(32, 24), dim3(256), 0, stream,
                     xb, WqkvT, qkbuf, VtBuf);
  hipLaunchKernelGGL(attn_kernel, dim3(32, 32), dim3(256), 0, stream,
                     qkbuf, VtBuf, Obuf);
  hipLaunchKernelGGL(gemm_out, dim3(32, 16), dim3(256), 0, stream,
                     Obuf, WoutT, bout, d_out, flagp);
}